// Round 1
// baseline (101.167 us; speedup 1.0000x reference)
//
#include <hip/hip_runtime.h>
#include <math.h>

#define FDIM  50
#define EDIM  16
#define ADIM  16
#define NPAIR 1225   // 50*49/2
#define ESTR  20     // padded LDS row stride (floats): 80B, 16B-aligned, bank period 8
#define KMAX  5      // ceil(1225/256)

__global__ __launch_bounds__(256) void afm_fwd(
    const int*   __restrict__ feat_index,
    const float* __restrict__ feat_value,
    const float* __restrict__ emb_table,
    const float* __restrict__ attn_w,
    const float* __restrict__ attn_b,
    const float* __restrict__ attn_h,
    const float* __restrict__ attn_p,
    const float* __restrict__ lin_w,
    const float* __restrict__ lin_b,
    float*       __restrict__ out)
{
    __shared__ __align__(16) float embLds[FDIM * ESTR];
    __shared__ __align__(16) float wtLds[ADIM * ESTR];   // wt[a][e] = W[e][a]
    __shared__ __align__(16) float pLds[EDIM];
    __shared__ float biasLds[ADIM];
    __shared__ float hLds[ADIM];
    __shared__ float lwLds[FDIM];
    __shared__ float ylinLds;
    __shared__ float wpart[8];

    const int b = blockIdx.x;
    const int t = threadIdx.x;

    // ---- stage constants (before first barrier) ----
    {
        int e = t >> 4, a = t & 15;          // attn_w is [E][A] row-major, t = e*16+a
        wtLds[a * ESTR + e] = attn_w[t];     // store transposed
    }
    if (t < ADIM) { biasLds[t] = attn_b[t]; hLds[t] = attn_h[t]; }
    if (t < EDIM) pLds[t] = attn_p[t];
    if (t < FDIM) lwLds[t] = lin_w[t];

    // ---- stage emb[f][e] = emb_table[idx[f]][e] * val[f] ----
    for (int idx = t; idx < FDIM * EDIM; idx += 256) {
        int f = idx >> 4, e = idx & 15;
        int fi   = feat_index[b * FDIM + f];
        float fv = feat_value[b * FDIM + f];
        embLds[f * ESTR + e] = emb_table[fi * EDIM + e] * fv;
    }
    __syncthreads();

    // ---- y_lin: lanes 0..15 of wave 0 ----
    if (t < EDIM) {
        float acc = lin_b[0];
        #pragma unroll
        for (int f = 0; f < FDIM; ++f)
            acc = fmaf(embLds[f * ESTR + t], lwLds[f], acc);
        acc = fmaxf(acc, 0.0f);
        #pragma unroll
        for (int off = 8; off >= 1; off >>= 1)
            acc += __shfl_down(acc, off, 16);
        if (t == 0) ylinLds = acc;
    }

    // ---- pair phase: each thread owns pairs p = t + 256k ----
    float ewp[KMAX][EDIM];
    float u[KMAX], s[KMAX];

    const float4 pv0 = *reinterpret_cast<const float4*>(&pLds[0]);
    const float4 pv1 = *reinterpret_cast<const float4*>(&pLds[4]);
    const float4 pv2 = *reinterpret_cast<const float4*>(&pLds[8]);
    const float4 pv3 = *reinterpret_cast<const float4*>(&pLds[12]);

    #pragma unroll
    for (int k = 0; k < KMAX; ++k) {
        int p  = t + 256 * k;
        int pc = (p < NPAIR) ? p : 0;
        // closed-form i from p, then integer fixup. Q(i) = 49i - i(i-1)/2
        float tq = 9801.0f - 8.0f * (float)pc;
        int ii = (int)((99.0f - sqrtf(tq)) * 0.5f);
        ii = max(0, min(48, ii));
        while (ii < 48 && (49 * (ii + 1) - (((ii + 1) * ii) >> 1)) <= pc) ++ii;
        while (ii > 0  && (49 * ii - ((ii * (ii - 1)) >> 1)) > pc) --ii;
        int q = 49 * ii - ((ii * (ii - 1)) >> 1);
        int i = ii;
        int j = ii + 1 + (pc - q);

        const float4* ei = reinterpret_cast<const float4*>(&embLds[i * ESTR]);
        const float4* ej = reinterpret_cast<const float4*>(&embLds[j * ESTR]);
        float4 a0 = ei[0], a1 = ei[1], a2 = ei[2], a3 = ei[3];
        float4 b0 = ej[0], b1 = ej[1], b2 = ej[2], b3 = ej[3];
        ewp[k][0]  = a0.x * b0.x;  ewp[k][1]  = a0.y * b0.y;
        ewp[k][2]  = a0.z * b0.z;  ewp[k][3]  = a0.w * b0.w;
        ewp[k][4]  = a1.x * b1.x;  ewp[k][5]  = a1.y * b1.y;
        ewp[k][6]  = a1.z * b1.z;  ewp[k][7]  = a1.w * b1.w;
        ewp[k][8]  = a2.x * b2.x;  ewp[k][9]  = a2.y * b2.y;
        ewp[k][10] = a2.z * b2.z;  ewp[k][11] = a2.w * b2.w;
        ewp[k][12] = a3.x * b3.x;  ewp[k][13] = a3.y * b3.y;
        ewp[k][14] = a3.z * b3.z;  ewp[k][15] = a3.w * b3.w;

        float uu = 0.0f;
        uu = fmaf(ewp[k][0],  pv0.x, uu); uu = fmaf(ewp[k][1],  pv0.y, uu);
        uu = fmaf(ewp[k][2],  pv0.z, uu); uu = fmaf(ewp[k][3],  pv0.w, uu);
        uu = fmaf(ewp[k][4],  pv1.x, uu); uu = fmaf(ewp[k][5],  pv1.y, uu);
        uu = fmaf(ewp[k][6],  pv1.z, uu); uu = fmaf(ewp[k][7],  pv1.w, uu);
        uu = fmaf(ewp[k][8],  pv2.x, uu); uu = fmaf(ewp[k][9],  pv2.y, uu);
        uu = fmaf(ewp[k][10], pv2.z, uu); uu = fmaf(ewp[k][11], pv2.w, uu);
        uu = fmaf(ewp[k][12], pv3.x, uu); uu = fmaf(ewp[k][13], pv3.y, uu);
        uu = fmaf(ewp[k][14], pv3.z, uu); uu = fmaf(ewp[k][15], pv3.w, uu);
        u[k] = uu;
        s[k] = 0.0f;
    }

    // a-outer sweep: one W^T row (16 floats, broadcast b128) serves 5 pairs
    #pragma unroll
    for (int a = 0; a < ADIM; ++a) {
        const float4* wr = reinterpret_cast<const float4*>(&wtLds[a * ESTR]);
        float4 w0 = wr[0], w1 = wr[1], w2 = wr[2], w3 = wr[3];
        float ba = biasLds[a], ha = hLds[a];
        #pragma unroll
        for (int k = 0; k < KMAX; ++k) {
            float acc = ba;
            acc = fmaf(ewp[k][0],  w0.x, acc); acc = fmaf(ewp[k][1],  w0.y, acc);
            acc = fmaf(ewp[k][2],  w0.z, acc); acc = fmaf(ewp[k][3],  w0.w, acc);
            acc = fmaf(ewp[k][4],  w1.x, acc); acc = fmaf(ewp[k][5],  w1.y, acc);
            acc = fmaf(ewp[k][6],  w1.z, acc); acc = fmaf(ewp[k][7],  w1.w, acc);
            acc = fmaf(ewp[k][8],  w2.x, acc); acc = fmaf(ewp[k][9],  w2.y, acc);
            acc = fmaf(ewp[k][10], w2.z, acc); acc = fmaf(ewp[k][11], w2.w, acc);
            acc = fmaf(ewp[k][12], w3.x, acc); acc = fmaf(ewp[k][13], w3.y, acc);
            acc = fmaf(ewp[k][14], w3.z, acc); acc = fmaf(ewp[k][15], w3.w, acc);
            s[k] = fmaf(fmaxf(acc, 0.0f), ha, s[k]);
        }
    }

    float den = 0.0f, ynum = 0.0f;
    #pragma unroll
    for (int k = 0; k < KMAX; ++k) {
        float sc = (t + 256 * k < NPAIR) ? __expf(s[k]) : 0.0f;
        den += sc;
        ynum = fmaf(sc, u[k], ynum);
    }

    // block reduce two scalars
    #pragma unroll
    for (int off = 32; off >= 1; off >>= 1) {
        den  += __shfl_down(den, off);
        ynum += __shfl_down(ynum, off);
    }
    int w = t >> 6;
    if ((t & 63) == 0) { wpart[w] = den; wpart[4 + w] = ynum; }
    __syncthreads();
    if (t == 0) {
        float D = wpart[0] + wpart[1] + wpart[2] + wpart[3];
        float N = wpart[4] + wpart[5] + wpart[6] + wpart[7];
        out[b] = N / D + ylinLds;
    }
}

extern "C" void kernel_launch(void* const* d_in, const int* in_sizes, int n_in,
                              void* d_out, int out_size, void* d_ws, size_t ws_size,
                              hipStream_t stream) {
    const int*   feat_index = (const int*)  d_in[0];
    const float* feat_value = (const float*)d_in[1];
    const float* emb_table  = (const float*)d_in[2];
    const float* attn_w     = (const float*)d_in[3];
    const float* attn_b     = (const float*)d_in[4];
    const float* attn_h     = (const float*)d_in[5];
    const float* attn_p     = (const float*)d_in[6];
    const float* lin_w      = (const float*)d_in[7];
    const float* lin_b      = (const float*)d_in[8];
    float* outp = (float*)d_out;

    dim3 grid(out_size);   // 8192 batch rows, one block each
    dim3 block(256);
    afm_fwd<<<grid, block, 0, stream>>>(feat_index, feat_value, emb_table,
                                        attn_w, attn_b, attn_h, attn_p,
                                        lin_w, lin_b, outp);
}

// Round 2
// 70.267 us; speedup vs baseline: 1.4398x; 1.4398x over previous
//
#include <hip/hip_runtime.h>
#include <math.h>

#define FDIM  50
#define EDIM  16
#define ADIM  16
#define NPAIR 1225
#define NTILE 77
#define NPAD  (NTILE * 16)   // 1232
#define HSTR  24             // halfs per emb row (48 B, 16B-aligned chunks)

typedef _Float16 half8  __attribute__((ext_vector_type(8)));
typedef _Float16 half2v __attribute__((ext_vector_type(2)));
typedef float    f32x4  __attribute__((ext_vector_type(4)));

__global__ __launch_bounds__(256) void afm_fwd(
    const int*   __restrict__ feat_index,
    const float* __restrict__ feat_value,
    const float* __restrict__ emb_table,
    const float* __restrict__ attn_w,
    const float* __restrict__ attn_b,
    const float* __restrict__ attn_h,
    const float* __restrict__ attn_p,
    const float* __restrict__ lin_w,
    const float* __restrict__ lin_b,
    float*       __restrict__ out)
{
    __shared__ __align__(16) _Float16 embH[FDIM * HSTR];  // 2400 B
    __shared__ unsigned ijLds[NPAD];                      // 4928 B: (i*48)<<16 | (j*48)
    __shared__ float lwLds[FDIM];
    __shared__ float ylinLds;
    __shared__ float wpart[8];

    const int t    = threadIdx.x;
    const int b    = blockIdx.x;
    const int lane = t & 63;
    const int wv   = t >> 6;
    const int g    = lane >> 4;   // K-chunk group (e-range g*8..g*8+7; g>=2 is zero-pad)
    const int pcol = lane & 15;   // pair-in-tile (B col) == attention col for A

    if (t < FDIM) lwLds[t] = lin_w[t];

    // stage emb[f][e] = emb_table[idx][e]*val as fp16
    for (int idx = t; idx < FDIM * EDIM; idx += 256) {
        int f = idx >> 4, e = idx & 15;
        int fi   = feat_index[b * FDIM + f];
        float fv = feat_value[b * FDIM + f];
        embH[f * HSTR + e] = (_Float16)(emb_table[fi * EDIM + e] * fv);
    }
    // pair -> (i,j) byte-offset table (once per block)
    for (int p = t; p < NPAD; p += 256) {
        int pc = (p < NPAIR) ? p : 0;
        float tq = 9801.0f - 8.0f * (float)pc;
        int ii = (int)((99.0f - sqrtf(tq)) * 0.5f);
        ii = max(0, min(48, ii));
        while (ii < 48 && (49 * (ii + 1) - (((ii + 1) * ii) >> 1)) <= pc) ++ii;
        while (ii > 0  && (49 * ii - ((ii * (ii - 1)) >> 1)) > pc) --ii;
        int q  = 49 * ii - ((ii * (ii - 1)) >> 1);
        int jj = ii + 1 + (pc - q);
        ijLds[p] = ((unsigned)(ii * (HSTR * 2)) << 16) | (unsigned)(jj * (HSTR * 2));
    }
    __syncthreads();

    // y_lin (lanes 0..15 of wave 0)
    if (t < EDIM) {
        float acc = lin_b[0];
        #pragma unroll
        for (int f = 0; f < FDIM; ++f)
            acc = fmaf((float)embH[f * HSTR + t], lwLds[f], acc);
        acc = fmaxf(acc, 0.0f);
        #pragma unroll
        for (int off = 8; off >= 1; off >>= 1)
            acc += __shfl_down(acc, off, 16);
        if (t == 0) ylinLds = acc;
    }

    // ---- per-lane constant fragments ----
    // A = W^T [16a x 32e(pad)]: lane holds row a=pcol, k=e=g*8+m
    half8 fragA;
    #pragma unroll
    for (int m = 0; m < 8; ++m) {
        int e = g * 8 + m;
        float w = (e < EDIM) ? attn_w[e * ADIM + pcol] : 0.0f;
        fragA[m] = (_Float16)w;
    }
    const int a0 = g * 4;   // D rows owned by this lane: a = a0 + reg
    const float bb0 = attn_b[a0 + 0], bb1 = attn_b[a0 + 1],
                bb2 = attn_b[a0 + 2], bb3 = attn_b[a0 + 3];
    const float hh0 = attn_h[a0 + 0], hh1 = attn_h[a0 + 1],
                hh2 = attn_h[a0 + 2], hh3 = attn_h[a0 + 3];
    half2v ph[4];
    #pragma unroll
    for (int m = 0; m < 4; ++m) {
        int e0 = g * 8 + 2 * m;
        float p0 = (e0     < EDIM) ? attn_p[e0]     : 0.0f;
        float p1 = (e0 + 1 < EDIM) ? attn_p[e0 + 1] : 0.0f;
        ph[m][0] = (_Float16)p0; ph[m][1] = (_Float16)p1;
    }

    const char* ebase = (const char*)embH;
    float den = 0.0f, num = 0.0f;

    for (int tile = wv; tile < NTILE; tile += 4) {
        int p = tile * 16 + pcol;
        unsigned ij = ijLds[p];
        half8 fragB = {0, 0, 0, 0, 0, 0, 0, 0};
        float ud = 0.0f;
        if (g < 2) {
            unsigned chunk = (unsigned)(g * 16);
            half8 ei = *(const half8*)(ebase + (ij >> 16) + chunk);
            half8 ej = *(const half8*)(ebase + (ij & 0xffffu) + chunk);
            fragB = ei * ej;   // v_pk_mul_f16 x4 — IS the B fragment
            half2v u2 = __builtin_shufflevector(fragB, fragB, 0, 1) * ph[0];
            u2 += __builtin_shufflevector(fragB, fragB, 2, 3) * ph[1];
            u2 += __builtin_shufflevector(fragB, fragB, 4, 5) * ph[2];
            u2 += __builtin_shufflevector(fragB, fragB, 6, 7) * ph[3];
            ud = (float)u2[0] + (float)u2[1];
        }
        // D[a][p] = W^T * ewp^T + bias : rows a=(g*4+reg), col p=pcol
        f32x4 acc = { bb0, bb1, bb2, bb3 };
        acc = __builtin_amdgcn_mfma_f32_16x16x32_f16(fragA, fragB, acc, 0, 0, 0);
        float sval = fmaxf(acc[0], 0.f) * hh0;
        sval = fmaf(fmaxf(acc[1], 0.f), hh1, sval);
        sval = fmaf(fmaxf(acc[2], 0.f), hh2, sval);
        sval = fmaf(fmaxf(acc[3], 0.f), hh3, sval);
        // sum over all 16 a: combine the 4 lane-groups
        sval += __shfl_xor(sval, 16);
        sval += __shfl_xor(sval, 32);
        float sc = (p < NPAIR) ? __expf(sval) : 0.0f;
        num = fmaf(sc, ud, num);       // each (pair, e-chunk) counted once (g<2 only, ud=0 else)
        if (g == 0) den += sc;         // count each pair exactly once
    }

    #pragma unroll
    for (int off = 32; off >= 1; off >>= 1) {
        den += __shfl_down(den, off);
        num += __shfl_down(num, off);
    }
    if (lane == 0) { wpart[wv] = den; wpart[4 + wv] = num; }
    __syncthreads();
    if (t == 0) {
        float D = wpart[0] + wpart[1] + wpart[2] + wpart[3];
        float N = wpart[4] + wpart[5] + wpart[6] + wpart[7];
        out[b] = N / D + ylinLds;
    }
}

extern "C" void kernel_launch(void* const* d_in, const int* in_sizes, int n_in,
                              void* d_out, int out_size, void* d_ws, size_t ws_size,
                              hipStream_t stream) {
    const int*   feat_index = (const int*)  d_in[0];
    const float* feat_value = (const float*)d_in[1];
    const float* emb_table  = (const float*)d_in[2];
    const float* attn_w     = (const float*)d_in[3];
    const float* attn_b     = (const float*)d_in[4];
    const float* attn_h     = (const float*)d_in[5];
    const float* attn_p     = (const float*)d_in[6];
    const float* lin_w      = (const float*)d_in[7];
    const float* lin_b      = (const float*)d_in[8];
    float* outp = (float*)d_out;

    dim3 grid(out_size);   // one block per batch row
    dim3 block(256);
    afm_fwd<<<grid, block, 0, stream>>>(feat_index, feat_value, emb_table,
                                        attn_w, attn_b, attn_h, attn_p,
                                        lin_w, lin_b, outp);
}

// Round 4
// 45.852 us; speedup vs baseline: 2.2064x; 1.5325x over previous
//
#include <hip/hip_runtime.h>
#include <math.h>

#define FDIM  50
#define EDIM  16
#define ADIM  16
#define NPAIR 1225
#define BROWS 16        // batch rows per block (MFMA cols)
#define NTHREADS 512
#define NWAVE 8
#define FBLK  512       // bytes per f-block in LDS: [chunk4][b16][8B]

typedef _Float16 half4  __attribute__((ext_vector_type(4)));
typedef _Float16 half2v __attribute__((ext_vector_type(2)));
typedef __fp16   h16x4  __attribute__((ext_vector_type(4)));
typedef __fp16   h16x2  __attribute__((ext_vector_type(2)));
typedef float    f32x4  __attribute__((ext_vector_type(4)));

__device__ inline f32x4 mfma16x16x16f16(half4 a, half4 b, f32x4 c) {
    return __builtin_amdgcn_mfma_f32_16x16x16f16(
        __builtin_bit_cast(h16x4, a), __builtin_bit_cast(h16x4, b), c, 0, 0, 0);
}

__global__ __launch_bounds__(NTHREADS) void afm_fwd(
    const int*   __restrict__ feat_index,
    const float* __restrict__ feat_value,
    const float* __restrict__ emb_table,
    const float* __restrict__ attn_w,
    const float* __restrict__ attn_b,
    const float* __restrict__ attn_h,
    const float* __restrict__ attn_p,
    const float* __restrict__ lin_w,
    const float* __restrict__ lin_b,
    float*       __restrict__ out)
{
    __shared__ __align__(16) _Float16 embLds[FDIM * 256]; // [f][c][b][4] = 25.6 KB
    __shared__ unsigned ijLds[NPAIR];                     // packed (i*512)<<16 | j*512
    __shared__ float    redLds[NWAVE][BROWS][2];
    __shared__ float    ylinLds[BROWS];
    __shared__ float    lwLds[FDIM];

    const int t    = threadIdx.x;
    const int lane = t & 63;
    const int wv   = t >> 6;
    const int g    = lane >> 4;
    const int col  = lane & 15;
    const int b0   = blockIdx.x * BROWS;

    if (t < FDIM) lwLds[t] = lin_w[t];

    // ---- ij offset table (per block; ~2.4 iters/thread) ----
    for (int p = t; p < NPAIR; p += NTHREADS) {
        float tq = 9801.0f - 8.0f * (float)p;
        int ii = (int)((99.0f - sqrtf(tq)) * 0.5f);
        ii = max(0, min(48, ii));
        while (ii < 48 && (49*(ii+1) - (((ii+1)*ii)>>1)) <= p) ++ii;
        while (ii > 0  && (49*ii - ((ii*(ii-1))>>1)) > p) --ii;
        int q  = 49*ii - ((ii*(ii-1))>>1);
        int jj = ii + 1 + (p - q);
        ijLds[p] = ((unsigned)(ii*FBLK) << 16) | (unsigned)(jj*FBLK);
    }

    // ---- stage emb: t -> (f = t>>4 [+32], b = t&15); layout [f][chunk][b][4] ----
    {
        int bb = t & 15;
        for (int f = t >> 4; f < FDIM; f += 32) {
            int   fi = feat_index[(b0 + bb) * FDIM + f];
            float fv = feat_value[(b0 + bb) * FDIM + f];
            const float4* tr = (const float4*)(emb_table + (size_t)fi * EDIM);
            #pragma unroll
            for (int c = 0; c < 4; ++c) {
                float4 tv = tr[c];
                half4 h;
                h[0] = (_Float16)(tv.x * fv);
                h[1] = (_Float16)(tv.y * fv);
                h[2] = (_Float16)(tv.z * fv);
                h[3] = (_Float16)(tv.w * fv);
                *(half4*)&embLds[f*256 + c*64 + bb*4] = h;
            }
        }
    }
    __syncthreads();

    // ---- y_lin: threads 0..255: b = t>>4, e = t&15 ----
    if (t < 256) {
        int bb = t >> 4, e = t & 15;
        int off = (e >> 2) * 64 + bb * 4 + (e & 3);
        float acc = lin_b[0];
        #pragma unroll
        for (int f = 0; f < FDIM; ++f)
            acc = fmaf((float)embLds[f*256 + off], lwLds[f], acc);
        acc = fmaxf(acc, 0.0f);
        acc += __shfl_xor(acc, 1);
        acc += __shfl_xor(acc, 2);
        acc += __shfl_xor(acc, 4);
        acc += __shfl_xor(acc, 8);
        if (e == 0) ylinLds[bb] = acc;
    }

    // ---- loop-invariant fragments ----
    // MFMA1: D1[a][b] = sum_e W^T[a][e] * ewp[e][b] + bias[a]
    //   A1: lane holds row a=col, k=e=g*4+m  -> W[e][a]
    // MFMA2: D2[r][b] = sum_a h[a] * relu1[a][b]   (rows identical)
    half4 fragA1, fragA2, ph;
    #pragma unroll
    for (int m = 0; m < 4; ++m) {
        int k = g * 4 + m;
        fragA1[m] = (_Float16)attn_w[k * ADIM + col];
        fragA2[m] = (_Float16)attn_h[k];
        ph[m]     = (_Float16)attn_p[k];
    }
    f32x4 biasC;
    #pragma unroll
    for (int m = 0; m < 4; ++m) biasC[m] = attn_b[g * 4 + m];
    const f32x4 zeroC = {0.f, 0.f, 0.f, 0.f};

    const char* ebase = (const char*)embLds;
    const unsigned laddr = (unsigned)lane * 8u;
    float num = 0.f, den = 0.f;

    #pragma unroll 2
    for (int p = wv; p < NPAIR; p += NWAVE) {
        unsigned u = ijLds[p];                       // wave-uniform -> LDS broadcast
        half4 ei = *(const half4*)(ebase + (u >> 16)     + laddr);
        half4 ej = *(const half4*)(ebase + (u & 0xffffu) + laddr);
        half4 prod = ei * ej;                        // B1 fragment (k=g*4+m, col=b)

        half2v plo = __builtin_shufflevector(prod, prod, 0, 1);
        half2v phi = __builtin_shufflevector(prod, prod, 2, 3);
        half2v qlo = __builtin_shufflevector(ph, ph, 0, 1);
        half2v qhi = __builtin_shufflevector(ph, ph, 2, 3);
#if __has_builtin(__builtin_amdgcn_fdot2)
        float ud = __builtin_amdgcn_fdot2(
                      __builtin_bit_cast(h16x2, plo), __builtin_bit_cast(h16x2, qlo),
                      __builtin_amdgcn_fdot2(
                          __builtin_bit_cast(h16x2, phi), __builtin_bit_cast(h16x2, qhi),
                          0.f, false),
                      false);
#else
        half2v q2 = plo * qlo + phi * qhi;
        float ud = (float)q2[0] + (float)q2[1];
#endif
        f32x4 acc1 = mfma16x16x16f16(fragA1, prod, biasC);
        h16x2 rlo = __builtin_amdgcn_cvt_pkrtz(fmaxf(acc1[0], 0.f), fmaxf(acc1[1], 0.f));
        h16x2 rhi = __builtin_amdgcn_cvt_pkrtz(fmaxf(acc1[2], 0.f), fmaxf(acc1[3], 0.f));
        half4 rfrag = __builtin_bit_cast(half4,
                        __builtin_shufflevector(rlo, rhi, 0, 1, 2, 3)); // B2 frag == C1 layout
        f32x4 acc2 = mfma16x16x16f16(fragA2, rfrag, zeroC);
        float sc = __expf(acc2[0]);                  // s[b] identical on all 4 g-groups
        num = fmaf(sc, ud, num);                     // ud covers this lane's 4 e's
        den += sc;                                   // counted 4x -> fixed at readout
    }

    // reduce the 4 g-groups (e-chunks) per b within the wave
    num += __shfl_xor(num, 16); num += __shfl_xor(num, 32);
    den += __shfl_xor(den, 16); den += __shfl_xor(den, 32);
    if (g == 0) { redLds[wv][col][0] = num; redLds[wv][col][1] = den; }
    __syncthreads();

    if (t < BROWS) {
        float nn = 0.f, dd = 0.f;
        #pragma unroll
        for (int w = 0; w < NWAVE; ++w) { nn += redLds[w][t][0]; dd += redLds[w][t][1]; }
        out[b0 + t] = 4.0f * nn / dd + ylinLds[t];   // den was counted 4x per pair
    }
}

extern "C" void kernel_launch(void* const* d_in, const int* in_sizes, int n_in,
                              void* d_out, int out_size, void* d_ws, size_t ws_size,
                              hipStream_t stream) {
    const int*   feat_index = (const int*)  d_in[0];
    const float* feat_value = (const float*)d_in[1];
    const float* emb_table  = (const float*)d_in[2];
    const float* attn_w     = (const float*)d_in[3];
    const float* attn_b     = (const float*)d_in[4];
    const float* attn_h     = (const float*)d_in[5];
    const float* attn_p     = (const float*)d_in[6];
    const float* lin_w      = (const float*)d_in[7];
    const float* lin_b      = (const float*)d_in[8];
    float* outp = (float*)d_out;

    dim3 grid(out_size / BROWS);   // 512 blocks of 16 batch rows
    dim3 block(NTHREADS);
    afm_fwd<<<grid, block, 0, stream>>>(feat_index, feat_value, emb_table,
                                        attn_w, attn_b, attn_h, attn_p,
                                        lin_w, lin_b, outp);
}

// Round 5
// 40.018 us; speedup vs baseline: 2.5280x; 1.1458x over previous
//
#include <hip/hip_runtime.h>
#include <math.h>

#define FDIM  50
#define EDIM  16
#define ADIM  16
#define NPAIR 1225
#define BROWS 16        // batch rows per block (MFMA cols)
#define NTHREADS 1024
#define NWAVE 16
#define FBLK  512       // bytes per f-block in LDS: [chunk4][b16][8B]

typedef _Float16 half4  __attribute__((ext_vector_type(4)));
typedef _Float16 half2v __attribute__((ext_vector_type(2)));
typedef __fp16   h16x4  __attribute__((ext_vector_type(4)));
typedef __fp16   h16x2  __attribute__((ext_vector_type(2)));
typedef float    f32x4  __attribute__((ext_vector_type(4)));

__device__ inline f32x4 mfma16x16x16f16(half4 a, half4 b, f32x4 c) {
    return __builtin_amdgcn_mfma_f32_16x16x16f16(
        __builtin_bit_cast(h16x4, a), __builtin_bit_cast(h16x4, b), c, 0, 0, 0);
}

__global__ __launch_bounds__(NTHREADS) void afm_fwd(
    const int*   __restrict__ feat_index,
    const float* __restrict__ feat_value,
    const float* __restrict__ emb_table,
    const float* __restrict__ attn_w,
    const float* __restrict__ attn_b,
    const float* __restrict__ attn_h,
    const float* __restrict__ attn_p,
    const float* __restrict__ lin_w,
    const float* __restrict__ lin_b,
    float*       __restrict__ out)
{
    __shared__ __align__(16) _Float16 embLds[FDIM * 256]; // [f][c][b][4] = 25.6 KB
    __shared__ unsigned ijLds[NPAIR];                     // packed (i*512)<<16 | j*512
    __shared__ float    redLds[NWAVE][BROWS][2];
    __shared__ float    ylinLds[BROWS];
    __shared__ float    lwLds[FDIM];

    const int t    = threadIdx.x;
    const int lane = t & 63;
    const int wv   = t >> 6;
    const int g    = lane >> 4;
    const int col  = lane & 15;
    const int b0   = blockIdx.x * BROWS;

    if (t < FDIM) lwLds[t] = lin_w[t];

    // ---- ij offset table (per block; ~1.2 iters/thread) ----
    for (int p = t; p < NPAIR; p += NTHREADS) {
        float tq = 9801.0f - 8.0f * (float)p;
        int ii = (int)((99.0f - sqrtf(tq)) * 0.5f);
        ii = max(0, min(48, ii));
        while (ii < 48 && (49*(ii+1) - (((ii+1)*ii)>>1)) <= p) ++ii;
        while (ii > 0  && (49*ii - ((ii*(ii-1))>>1)) > p) --ii;
        int q  = 49*ii - ((ii*(ii-1))>>1);
        int jj = ii + 1 + (p - q);
        ijLds[p] = ((unsigned)(ii*FBLK) << 16) | (unsigned)(jj*FBLK);
    }

    // ---- stage emb: t -> (f = t>>4, b = t&15); layout [f][chunk][b][4] ----
    {
        int bb = t & 15;
        int f  = t >> 4;               // 0..63, one pass (f<50 active)
        if (f < FDIM) {
            int   fi = feat_index[(b0 + bb) * FDIM + f];
            float fv = feat_value[(b0 + bb) * FDIM + f];
            const float4* tr = (const float4*)(emb_table + (size_t)fi * EDIM);
            #pragma unroll
            for (int c = 0; c < 4; ++c) {
                float4 tv = tr[c];
                half4 h;
                h[0] = (_Float16)(tv.x * fv);
                h[1] = (_Float16)(tv.y * fv);
                h[2] = (_Float16)(tv.z * fv);
                h[3] = (_Float16)(tv.w * fv);
                *(half4*)&embLds[f*256 + c*64 + bb*4] = h;
            }
        }
    }
    __syncthreads();

    // ---- y_lin: threads 0..255: b = t>>4, e = t&15 ----
    if (t < 256) {
        int bb = t >> 4, e = t & 15;
        int off = (e >> 2) * 64 + bb * 4 + (e & 3);
        float acc = lin_b[0];
        #pragma unroll
        for (int f = 0; f < FDIM; ++f)
            acc = fmaf((float)embLds[f*256 + off], lwLds[f], acc);
        acc = fmaxf(acc, 0.0f);
        acc += __shfl_xor(acc, 1);
        acc += __shfl_xor(acc, 2);
        acc += __shfl_xor(acc, 4);
        acc += __shfl_xor(acc, 8);
        if (e == 0) ylinLds[bb] = acc;
    }

    // ---- loop-invariant fragments ----
    // MFMA1: D1[a][b] = sum_e W^T[a][e] * ewp[e][b] + bias[a]
    //   A1: lane holds row a=col, k=e=g*4+m  -> W[e][a]
    // MFMA2: D2[r][b] = sum_a h[a] * relu1[a][b]   (rows identical)
    half4 fragA1, fragA2, ph;
    #pragma unroll
    for (int m = 0; m < 4; ++m) {
        int k = g * 4 + m;
        fragA1[m] = (_Float16)attn_w[k * ADIM + col];
        fragA2[m] = (_Float16)attn_h[k];
        ph[m]     = (_Float16)attn_p[k];
    }
    f32x4 biasC;
    #pragma unroll
    for (int m = 0; m < 4; ++m) biasC[m] = attn_b[g * 4 + m];
    const f32x4 zeroC = {0.f, 0.f, 0.f, 0.f};

    const char* ebase = (const char*)embLds;
    const unsigned laddr = (unsigned)lane * 8u;
    float num = 0.f, den = 0.f;

    #pragma unroll 4
    for (int p = wv; p < NPAIR; p += NWAVE) {
        unsigned u = ijLds[p];                       // wave-uniform -> LDS broadcast
        half4 ei = *(const half4*)(ebase + (u >> 16)     + laddr);
        half4 ej = *(const half4*)(ebase + (u & 0xffffu) + laddr);
        half4 prod = ei * ej;                        // B1 fragment (k=g*4+m, col=b)

        half2v plo = __builtin_shufflevector(prod, prod, 0, 1);
        half2v phi = __builtin_shufflevector(prod, prod, 2, 3);
        half2v qlo = __builtin_shufflevector(ph, ph, 0, 1);
        half2v qhi = __builtin_shufflevector(ph, ph, 2, 3);
#if __has_builtin(__builtin_amdgcn_fdot2)
        float ud = __builtin_amdgcn_fdot2(
                      __builtin_bit_cast(h16x2, plo), __builtin_bit_cast(h16x2, qlo),
                      __builtin_amdgcn_fdot2(
                          __builtin_bit_cast(h16x2, phi), __builtin_bit_cast(h16x2, qhi),
                          0.f, false),
                      false);
#else
        half2v q2 = plo * qlo + phi * qhi;
        float ud = (float)q2[0] + (float)q2[1];
#endif
        f32x4 acc1 = mfma16x16x16f16(fragA1, prod, biasC);
        h16x2 rlo = __builtin_amdgcn_cvt_pkrtz(fmaxf(acc1[0], 0.f), fmaxf(acc1[1], 0.f));
        h16x2 rhi = __builtin_amdgcn_cvt_pkrtz(fmaxf(acc1[2], 0.f), fmaxf(acc1[3], 0.f));
        half4 rfrag = __builtin_bit_cast(half4,
                        __builtin_shufflevector(rlo, rhi, 0, 1, 2, 3)); // B2 frag == C1 layout
        f32x4 acc2 = mfma16x16x16f16(fragA2, rfrag, zeroC);
        float sc = __expf(acc2[0]);                  // s[b] identical on all 4 g-groups
        num = fmaf(sc, ud, num);                     // ud covers this lane's 4 e's
        den += sc;                                   // counted 4x -> fixed at readout
    }

    // reduce the 4 g-groups (e-chunks) per b within the wave
    num += __shfl_xor(num, 16); num += __shfl_xor(num, 32);
    den += __shfl_xor(den, 16); den += __shfl_xor(den, 32);
    if (g == 0) { redLds[wv][col][0] = num; redLds[wv][col][1] = den; }
    __syncthreads();

    if (t < BROWS) {
        float nn = 0.f, dd = 0.f;
        #pragma unroll
        for (int w = 0; w < NWAVE; ++w) { nn += redLds[w][t][0]; dd += redLds[w][t][1]; }
        out[b0 + t] = 4.0f * nn / dd + ylinLds[t];   // den was counted 4x per pair
    }
}

extern "C" void kernel_launch(void* const* d_in, const int* in_sizes, int n_in,
                              void* d_out, int out_size, void* d_ws, size_t ws_size,
                              hipStream_t stream) {
    const int*   feat_index = (const int*)  d_in[0];
    const float* feat_value = (const float*)d_in[1];
    const float* emb_table  = (const float*)d_in[2];
    const float* attn_w     = (const float*)d_in[3];
    const float* attn_b     = (const float*)d_in[4];
    const float* attn_h     = (const float*)d_in[5];
    const float* attn_p     = (const float*)d_in[6];
    const float* lin_w      = (const float*)d_in[7];
    const float* lin_b      = (const float*)d_in[8];
    float* outp = (float*)d_out;

    dim3 grid(out_size / BROWS);   // 512 blocks of 16 batch rows
    dim3 block(NTHREADS);
    afm_fwd<<<grid, block, 0, stream>>>(feat_index, feat_value, emb_table,
                                        attn_w, attn_b, attn_h, attn_p,
                                        lin_w, lin_b, outp);
}